// Round 5
// baseline (402.610 us; speedup 1.0000x reference)
//
#include <hip/hip_runtime.h>
#include <hip/hip_bf16.h>

constexpr int D = 64;
constexpr int NBUCK = 8;    // one bucket per XCD
constexpr int NBLK = 1024;  // binning blocks

// ---------- fp32 -> bf16 row conversion ----------
__global__ void k_to_bf16(const float* __restrict__ in, __hip_bfloat16* __restrict__ out,
                          size_t m) {
    size_t i = (size_t)blockIdx.x * blockDim.x + threadIdx.x;
    if (i < m) out[i] = __float2bfloat16(in[i]);
}

// ---------- dst-binning (deterministic multisplit, no global atomics) ----------
__global__ void k_bin_hist(const int* __restrict__ dst, int* __restrict__ hist,
                           int e, int bdiv) {
    __shared__ int h[NBUCK];
    if (threadIdx.x < NBUCK) h[threadIdx.x] = 0;
    __syncthreads();
    for (int i = blockIdx.x * blockDim.x + threadIdx.x; i < e; i += gridDim.x * blockDim.x)
        atomicAdd(&h[(unsigned)dst[i] / (unsigned)bdiv], 1);  // LDS atomic
    __syncthreads();
    if (threadIdx.x < NBUCK) hist[threadIdx.x * NBLK + blockIdx.x] = h[threadIdx.x];
}

__global__ void k_bin_write(const int* __restrict__ src, const int* __restrict__ dst,
                            const int* __restrict__ histS,
                            int* __restrict__ bsrc, int* __restrict__ bdst,
                            int e, int bdiv) {
    __shared__ int cur[NBUCK];
    if (threadIdx.x < NBUCK) cur[threadIdx.x] = histS[threadIdx.x * NBLK + blockIdx.x];
    __syncthreads();
    for (int i = blockIdx.x * blockDim.x + threadIdx.x; i < e; i += gridDim.x * blockDim.x) {
        int s = src[i], d = dst[i];
        int slot = atomicAdd(&cur[(unsigned)d / (unsigned)bdiv], 1);  // LDS atomic
        bsrc[slot] = s;
        bdst[slot] = d;
    }
}

// ---------- generic scan helpers ----------
__global__ void k_scan1(const int* __restrict__ in, int* __restrict__ out,
                        int* __restrict__ bsum, int n) {
    __shared__ int s[1024];
    int tid = threadIdx.x, gid = blockIdx.x * 1024 + tid;
    int v = (gid < n) ? in[gid] : 0;
    s[tid] = v;
    __syncthreads();
    for (int o = 1; o < 1024; o <<= 1) {
        int t = (tid >= o) ? s[tid - o] : 0;
        __syncthreads();
        s[tid] += t;
        __syncthreads();
    }
    if (gid < n) out[gid] = s[tid] - v;  // exclusive within block
    if (tid == 1023) bsum[blockIdx.x] = s[1023];
}

__global__ void k_scan2(int* __restrict__ bsum, int nb) {
    if (threadIdx.x == 0) {
        int run = 0;
        for (int i = 0; i < nb; ++i) { int v = bsum[i]; bsum[i] = run; run += v; }
    }
}

__global__ void k_finalize(const int* __restrict__ tmp, const int* __restrict__ bsum,
                           int* __restrict__ out, int m) {
    int i = blockIdx.x * blockDim.x + threadIdx.x;
    if (i < m) out[i] = tmp[i] + bsum[i >> 10];
}

__global__ void k_scan3(const int* __restrict__ cnt, int* __restrict__ off,
                        const int* __restrict__ bsum, int* __restrict__ cur,
                        float* __restrict__ dinv, int n, int e) {
    int i = blockIdx.x * blockDim.x + threadIdx.x;
    if (i < n) {
        int o = off[i] + bsum[i >> 10];
        off[i] = o;
        cur[i] = o;
        dinv[i] = rsqrtf((float)(cnt[i] + 1));
        if (i == 0) off[n] = e;
    }
}

// ---------- XCD-owned count / fill ----------
__global__ void k_count_own(const int* __restrict__ bdst, const int* __restrict__ histS,
                            int* __restrict__ cnt, int e) {
    int p = blockIdx.x & (NBUCK - 1);
    int sub = blockIdx.x >> 3;
    int nsub = gridDim.x >> 3;
    int lo = histS[p * NBLK];
    int hi = (p == NBUCK - 1) ? e : histS[(p + 1) * NBLK];
    for (int i = lo + sub * blockDim.x + threadIdx.x; i < hi; i += nsub * blockDim.x)
        atomicAdd(&cnt[bdst[i]], 1);
}

__global__ void k_fill_own(const int* __restrict__ bsrc, const int* __restrict__ bdst,
                           const int* __restrict__ histS, int* __restrict__ cur,
                           int* __restrict__ csr, int e) {
    int p = blockIdx.x & (NBUCK - 1);
    int sub = blockIdx.x >> 3;
    int nsub = gridDim.x >> 3;
    int lo = histS[p * NBLK];
    int hi = (p == NBUCK - 1) ? e : histS[(p + 1) * NBLK];
    for (int i = lo + sub * blockDim.x + threadIdx.x; i < hi; i += nsub * blockDim.x) {
        int d = bdst[i];
        int slot = atomicAdd(&cur[d], 1);
        csr[slot] = bsrc[i];
    }
}

// ---------- fused aggregate + dense (one wave per node, bf16 gather) ----------
// row_i = dinv[i] * sum_{j in {i} ∪ nbrs(i)} dinv[src_j]*xin[src_j]   (xin pre-relu'd for L2)
// out_i = row_i @ W + b ; store fp32 (L2) or relu+bf16 (L1 output feeding L2)
template <bool STORE_RELU_BF16>
__global__ void k_agg_mm(const __hip_bfloat16* __restrict__ xin, const float* __restrict__ W,
                         const float* __restrict__ b,
                         const int* __restrict__ off, const int* __restrict__ csr,
                         const float* __restrict__ dinv,
                         float* __restrict__ outf, __hip_bfloat16* __restrict__ outb, int n) {
    __shared__ float sW[D][D];   // 16 KB
    __shared__ float sS[4][D];   // per-wave aggregated row staging
    int tid = threadIdx.x;       // 256 threads = 4 waves = 4 nodes
    for (int i = tid; i < D * D; i += 256) sW[i >> 6][i & 63] = W[i];
    int lane = tid & 63;
    int w = tid >> 6;
    int node = blockIdx.x * 4 + w;
    float acc = 0.f;
    if (node < n) {
        float dnode = dinv[node];
        acc = __bfloat162float(xin[(size_t)node * D + lane]) * dnode;  // self-loop
        int j = off[node], end = off[node + 1];
        for (; j + 7 < end; j += 8) {  // 8 gather rows in flight
            int s0 = csr[j], s1 = csr[j + 1], s2 = csr[j + 2], s3 = csr[j + 3];
            int s4 = csr[j + 4], s5 = csr[j + 5], s6 = csr[j + 6], s7 = csr[j + 7];
            float v0 = __bfloat162float(xin[(size_t)s0 * D + lane]);
            float v1 = __bfloat162float(xin[(size_t)s1 * D + lane]);
            float v2 = __bfloat162float(xin[(size_t)s2 * D + lane]);
            float v3 = __bfloat162float(xin[(size_t)s3 * D + lane]);
            float v4 = __bfloat162float(xin[(size_t)s4 * D + lane]);
            float v5 = __bfloat162float(xin[(size_t)s5 * D + lane]);
            float v6 = __bfloat162float(xin[(size_t)s6 * D + lane]);
            float v7 = __bfloat162float(xin[(size_t)s7 * D + lane]);
            acc = fmaf(v0, dinv[s0], acc);
            acc = fmaf(v1, dinv[s1], acc);
            acc = fmaf(v2, dinv[s2], acc);
            acc = fmaf(v3, dinv[s3], acc);
            acc = fmaf(v4, dinv[s4], acc);
            acc = fmaf(v5, dinv[s5], acc);
            acc = fmaf(v6, dinv[s6], acc);
            acc = fmaf(v7, dinv[s7], acc);
        }
        for (; j < end; ++j) {
            int s = csr[j];
            acc = fmaf(__bfloat162float(xin[(size_t)s * D + lane]), dinv[s], acc);
        }
        acc *= dnode;
    }
    sS[w][lane] = acc;
    __syncthreads();
    if (node < n) {
        float o = b[lane];
#pragma unroll
        for (int k = 0; k < D; ++k)
            o = fmaf(sS[w][k], sW[k][lane], o);  // sS broadcast, sW 2-way alias: conflict-free
        if (STORE_RELU_BF16)
            outb[(size_t)node * D + lane] = __float2bfloat16(fmaxf(o, 0.f));
        else
            outf[(size_t)node * D + lane] = o;
    }
}

extern "C" void kernel_launch(void* const* d_in, const int* in_sizes, int n_in,
                              void* d_out, int out_size, void* d_ws, size_t ws_size,
                              hipStream_t stream) {
    const float* x  = (const float*)d_in[0];
    const float* W1 = (const float*)d_in[1];
    const float* b1 = (const float*)d_in[2];
    const float* W2 = (const float*)d_in[3];
    const float* b2 = (const float*)d_in[4];
    const int*   ei = (const int*)d_in[5];

    const int n = in_sizes[0] / D;   // 100000
    const int e = in_sizes[5] / 2;   // 1600000
    const int* src = ei;
    const int* dst = ei + e;
    float* out = (float*)d_out;
    const int bdiv = (n + NBUCK - 1) / NBUCK;

    // workspace carve-out (256B-aligned chunks)
    char* base = (char*)d_ws;
    auto alloc = [&](size_t bytes) {
        void* p = (void*)base;
        base += (bytes + 255) & ~(size_t)255;
        return p;
    };
    float* dinv  = (float*)alloc((size_t)n * 4);
    int*   cnt   = (int*)alloc((size_t)n * 4);
    int*   off   = (int*)alloc((size_t)(n + 1) * 4);
    int*   cur   = (int*)alloc((size_t)n * 4);
    int*   bsum  = (int*)alloc(1024 * 4);
    int*   hist  = (int*)alloc((size_t)NBUCK * NBLK * 4);
    int*   histT = (int*)alloc((size_t)NBUCK * NBLK * 4);
    int*   histS = (int*)alloc((size_t)NBUCK * NBLK * 4);
    int*   bsrc  = (int*)alloc((size_t)e * 4);
    int*   bdst  = (int*)alloc((size_t)e * 4);
    int*   csr   = (int*)alloc((size_t)e * 4);
    __hip_bfloat16* xb  = (__hip_bfloat16*)alloc((size_t)n * D * 2);
    __hip_bfloat16* h1b = (__hip_bfloat16*)alloc((size_t)n * D * 2);

    const int B = 256;
    const int nb = (n + 1023) / 1024;
    const int M = NBUCK * NBLK;  // 8192

    hipMemsetAsync(cnt, 0, (size_t)n * 4, stream);

    // x -> bf16 (gather operand for layer 1)
    k_to_bf16<<<(int)(((size_t)n * D + B - 1) / B), B, 0, stream>>>(x, xb, (size_t)n * D);

    // bin edges by dst range (deterministic multisplit)
    k_bin_hist<<<NBLK, B, 0, stream>>>(dst, hist, e, bdiv);
    k_scan1<<<M / 1024, 1024, 0, stream>>>(hist, histT, bsum, M);
    k_scan2<<<1, 64, 0, stream>>>(bsum, M / 1024);
    k_finalize<<<(M + B - 1) / B, B, 0, stream>>>(histT, bsum, histS, M);
    k_bin_write<<<NBLK, B, 0, stream>>>(src, dst, histS, bsrc, bdst, e, bdiv);

    // XCD-owned degree count, then scan -> off/cur/dinv
    k_count_own<<<2048, B, 0, stream>>>(bdst, histS, cnt, e);
    k_scan1<<<nb, 1024, 0, stream>>>(cnt, off, bsum, n);
    k_scan2<<<1, 64, 0, stream>>>(bsum, nb);
    k_scan3<<<(n + B - 1) / B, B, 0, stream>>>(cnt, off, bsum, cur, dinv, n, e);

    // XCD-owned CSR fill
    k_fill_own<<<2048, B, 0, stream>>>(bsrc, bdst, histS, cur, csr, e);

    // layer 1: h1b = relu((Â x) @ W1 + b1), stored bf16
    k_agg_mm<true><<<(n + 3) / 4, B, 0, stream>>>(xb, W1, b1, off, csr, dinv,
                                                  nullptr, h1b, n);
    // layer 2: out = (Â h1b) @ W2 + b2, fp32
    k_agg_mm<false><<<(n + 3) / 4, B, 0, stream>>>(h1b, W2, b2, off, csr, dinv,
                                                   out, nullptr, n);
}